// Round 1
// baseline (414.069 us; speedup 1.0000x reference)
//
#include <hip/hip_runtime.h>
#include <hip/hip_bf16.h>
#include <stdint.h>

// B=4, T=2048, D_MODEL=1024, H=16, hd=64
// Q/K/V/O token-major layout: [B*T, 1024] with head h at cols h*64..h*64+63.

typedef __attribute__((ext_vector_type(8))) short short8;    // 8 x bf16 (4 VGPRs)
typedef __attribute__((ext_vector_type(4))) short short4v;
typedef __attribute__((ext_vector_type(4))) float floatx4;

#define LOG2E 1.4426950408889634f

__device__ __forceinline__ void gload_lds16(const void* g, void* l) {
  __builtin_amdgcn_global_load_lds(
      (const __attribute__((address_space(1))) void*)g,
      (__attribute__((address_space(3))) void*)l, 16, 0, 0);
}

__device__ __forceinline__ short f2bf(float f) {
  __hip_bfloat16 h = __float2bfloat16(f);
  return *reinterpret_cast<short*>(&h);
}

// ---------------- fp32 -> bf16 conversion ----------------
__global__ __launch_bounds__(256) void cvt_f32_bf16(const float* __restrict__ src,
                                                    short* __restrict__ dst, int n4) {
  const int i = blockIdx.x * blockDim.x + threadIdx.x;
  if (i >= n4) return;
  const float4 v = reinterpret_cast<const float4*>(src)[i];
  short4v o;
  o.x = f2bf(v.x); o.y = f2bf(v.y); o.z = f2bf(v.z); o.w = f2bf(v.w);
  reinterpret_cast<short4v*>(dst)[i] = o;
}

// ---------------- bf16 GEMM, C[m,n] = sum_k A[m,k]*B[n,k] ----------------
// 128x128 tile, BK=64, 256 threads (2x2 waves of 64x64), global_load_lds w=16,
// st-style XOR swizzle: logical 16B chunk c of row r lives at LDS chunk c^(r&7).
template <bool BF16OUT>
__device__ __forceinline__ void gemm_bt_body(const short* __restrict__ A,
                                             const short* __restrict__ B,
                                             void* __restrict__ Cout,
                                             int M, int N, int K, int m0, int n0) {
  __shared__ short lds_a[128 * 64];
  __shared__ short lds_b[128 * 64];
  const int tid = threadIdx.x;
  const int lane = tid & 63;
  const int w = tid >> 6;
  const int wm = w >> 1, wn = w & 1;
  const int lrow = lane & 15, lgrp = lane >> 4;

  floatx4 acc[4][4] = {};

  const int nkt = K >> 6;
  for (int kt = 0; kt < nkt; ++kt) {
    __syncthreads();
#pragma unroll
    for (int i = 0; i < 4; ++i) {  // stage A: 128 rows x 64 bf16 = 16KB
      const int chunk = i * 256 + tid;       // 0..1023
      const int row = chunk >> 3;            // 8 chunks per row
      const int cb = (chunk & 7) ^ (row & 7);  // inverse-swizzled source chunk
      gload_lds16(A + (size_t)(m0 + row) * K + kt * 64 + cb * 8, &lds_a[chunk * 8]);
    }
#pragma unroll
    for (int i = 0; i < 4; ++i) {  // stage B
      const int chunk = i * 256 + tid;
      const int row = chunk >> 3;
      const int cb = (chunk & 7) ^ (row & 7);
      gload_lds16(B + (size_t)(n0 + row) * K + kt * 64 + cb * 8, &lds_b[chunk * 8]);
    }
    __syncthreads();
#pragma unroll
    for (int ks = 0; ks < 2; ++ks) {
      short8 af[4], bfr[4];
#pragma unroll
      for (int mf = 0; mf < 4; ++mf) {
        const int row = wm * 64 + mf * 16 + lrow;
        const int cir = (ks * 4 + lgrp) ^ (row & 7);
        af[mf] = *reinterpret_cast<const short8*>(&lds_a[row * 64 + cir * 8]);
      }
#pragma unroll
      for (int nf = 0; nf < 4; ++nf) {
        const int row = wn * 64 + nf * 16 + lrow;
        const int cir = (ks * 4 + lgrp) ^ (row & 7);
        bfr[nf] = *reinterpret_cast<const short8*>(&lds_b[row * 64 + cir * 8]);
      }
#pragma unroll
      for (int mf = 0; mf < 4; ++mf)
#pragma unroll
        for (int nf = 0; nf < 4; ++nf)
          acc[mf][nf] =
              __builtin_amdgcn_mfma_f32_16x16x32_bf16(af[mf], bfr[nf], acc[mf][nf], 0, 0, 0);
    }
  }

  // epilogue: D row=(lane>>4)*4+r, col=lane&15 (verified m89/m91 mapping)
#pragma unroll
  for (int mf = 0; mf < 4; ++mf) {
#pragma unroll
    for (int nf = 0; nf < 4; ++nf) {
#pragma unroll
      for (int r = 0; r < 4; ++r) {
        const int grow = m0 + wm * 64 + mf * 16 + lgrp * 4 + r;
        const int gcol = n0 + wn * 64 + nf * 16 + lrow;
        if (BF16OUT)
          reinterpret_cast<short*>(Cout)[(size_t)grow * N + gcol] = f2bf(acc[mf][nf][r]);
        else
          reinterpret_cast<float*>(Cout)[(size_t)grow * N + gcol] = acc[mf][nf][r];
      }
    }
  }
}

__global__ __launch_bounds__(256) void gemm_qkv(
    const short* __restrict__ xb, const short* __restrict__ wq, const short* __restrict__ wk,
    const short* __restrict__ wv, short* __restrict__ Qb, short* __restrict__ Kb,
    short* __restrict__ Vb) {
  const short* Bm;
  short* Cm;
  if (blockIdx.z == 0) { Bm = wq; Cm = Qb; }
  else if (blockIdx.z == 1) { Bm = wk; Cm = Kb; }
  else { Bm = wv; Cm = Vb; }
  gemm_bt_body<true>(xb, Bm, Cm, 8192, 1024, 1024, blockIdx.x * 128, blockIdx.y * 128);
}

__global__ __launch_bounds__(256) void gemm_out(const short* __restrict__ Ob,
                                                const short* __restrict__ wo,
                                                float* __restrict__ out) {
  gemm_bt_body<false>(Ob, wo, out, 8192, 1024, 1024, blockIdx.x * 128, blockIdx.y * 128);
}

// ---------------- flash attention (causal), bf16 in/out ----------------
// grid (32 q-tiles, 64 b*h), 256 threads = 4 waves, each wave owns 16 q rows.
__global__ __launch_bounds__(256) void attn_fwd(const short* __restrict__ Q,
                                                const short* __restrict__ K,
                                                const short* __restrict__ V,
                                                short* __restrict__ O) {
  __shared__ short lds_k[64 * 64];       // K tile, swizzled
  __shared__ short lds_vt[64 * 64];      // V^T tile, swizzled
  __shared__ short lds_p[4][16 * 64];    // per-wave P, swizzled

  const int tid = threadIdx.x;
  const int lane = tid & 63;
  const int w = tid >> 6;
  const int lrow = lane & 15, lgrp = lane >> 4;
  const int qt = blockIdx.x;
  const int bh = blockIdx.y;
  const int b = bh >> 4, h = bh & 15;

  const size_t base = (size_t)b * 2048 * 1024 + h * 64;

  // Q A-fragments hoisted to registers: lane holds Q[row=lrow][k=lgrp*8+j(+32*ks)]
  short8 qf[2];
  {
    const short* qp = Q + base + (size_t)(qt * 64 + w * 16 + lrow) * 1024 + lgrp * 8;
    qf[0] = *reinterpret_cast<const short8*>(qp);
    qf[1] = *reinterpret_cast<const short8*>(qp + 32);
  }

  floatx4 oacc[4] = {};
  float m_run[4], l_run[4];
#pragma unroll
  for (int r = 0; r < 4; ++r) { m_run[r] = -1e30f; l_run[r] = 0.f; }

  for (int kb = 0; kb <= qt; ++kb) {
    __syncthreads();
    // stage K tile (64x64) via global_load_lds, pre-swizzled source
#pragma unroll
    for (int i = 0; i < 2; ++i) {
      const int chunk = i * 256 + tid;   // 0..511
      const int row = chunk >> 3;
      const int cb = (chunk & 7) ^ (row & 7);
      gload_lds16(K + base + (size_t)(kb * 64 + row) * 1024 + cb * 8, &lds_k[chunk * 8]);
    }
    // stage V^T: lane reads V[kb*64+lane][dseg*8..+8], scatters to vt[d][k] (swizzled)
#pragma unroll
    for (int i = 0; i < 2; ++i) {
      const int dseg = i * 4 + w;  // 0..7
      const short8 vv = *reinterpret_cast<const short8*>(
          V + base + (size_t)(kb * 64 + lane) * 1024 + dseg * 8);
#pragma unroll
      for (int j = 0; j < 8; ++j) {
        const int d = dseg * 8 + j;
        lds_vt[d * 64 + ((((lane >> 3) ^ (d & 7)) << 3) | (lane & 7))] = vv[j];
      }
    }
    __syncthreads();

    // S = Q K^T : 16 q rows x 64 k cols per wave
    floatx4 s[4];
#pragma unroll
    for (int nf = 0; nf < 4; ++nf) {
      floatx4 z = {};
#pragma unroll
      for (int ks = 0; ks < 2; ++ks) {
        const int row = nf * 16 + lrow;
        const int cir = (ks * 4 + lgrp) ^ (row & 7);
        const short8 kf = *reinterpret_cast<const short8*>(&lds_k[row * 64 + cir * 8]);
        z = __builtin_amdgcn_mfma_f32_16x16x32_bf16(qf[ks], kf, z, 0, 0, 0);
      }
      s[nf] = z;
    }

    // scale + causal mask + per-row max (rows of this lane's group: lgrp*4+r)
    const bool diag = (kb == qt);
    float sv[4][4], vmax[4];
#pragma unroll
    for (int r = 0; r < 4; ++r) vmax[r] = -1e30f;
#pragma unroll
    for (int nf = 0; nf < 4; ++nf) {
#pragma unroll
      for (int r = 0; r < 4; ++r) {
        float xv = s[nf][r] * 0.125f;
        if (diag) {
          const int kcol = nf * 16 + lrow;            // local col (tile == diag tile)
          const int qrow = w * 16 + lgrp * 4 + r;     // local row
          if (kcol > qrow) xv = -1e30f;
        }
        sv[nf][r] = xv;
        vmax[r] = fmaxf(vmax[r], xv);
      }
    }
#pragma unroll
    for (int d = 1; d < 16; d <<= 1)
#pragma unroll
      for (int r = 0; r < 4; ++r)
        vmax[r] = fmaxf(vmax[r], __shfl_xor(vmax[r], d, 64));

    float alpha[4], psum[4];
#pragma unroll
    for (int r = 0; r < 4; ++r) {
      const float mnew = fmaxf(m_run[r], vmax[r]);
      alpha[r] = exp2f((m_run[r] - mnew) * LOG2E);
      m_run[r] = mnew;
      psum[r] = 0.f;
    }

    // P = exp(S - m), write bf16 to per-wave LDS (swizzled), accumulate row sums
#pragma unroll
    for (int nf = 0; nf < 4; ++nf) {
#pragma unroll
      for (int r = 0; r < 4; ++r) {
        const float p = exp2f((sv[nf][r] - m_run[r]) * LOG2E);
        psum[r] += p;
        const int prow = lgrp * 4 + r;
        const int pcol = nf * 16 + lrow;
        lds_p[w][prow * 64 + (((pcol >> 3) ^ (prow & 7)) << 3) + (pcol & 7)] = f2bf(p);
      }
    }
#pragma unroll
    for (int d = 1; d < 16; d <<= 1)
#pragma unroll
      for (int r = 0; r < 4; ++r) psum[r] += __shfl_xor(psum[r], d, 64);

#pragma unroll
    for (int r = 0; r < 4; ++r) l_run[r] = l_run[r] * alpha[r] + psum[r];

    // rescale O accumulator
#pragma unroll
    for (int nf = 0; nf < 4; ++nf)
#pragma unroll
      for (int r = 0; r < 4; ++r) oacc[nf][r] *= alpha[r];

    __syncthreads();  // ensure P writes visible (belt-and-suspenders; per-wave region)

    // O += P @ V   (A = P from lds_p, B = V^T from lds_vt)
#pragma unroll
    for (int ks = 0; ks < 2; ++ks) {
      const int cirp = (ks * 4 + lgrp) ^ (lrow & 7);
      const short8 pf = *reinterpret_cast<const short8*>(&lds_p[w][lrow * 64 + cirp * 8]);
#pragma unroll
      for (int nf = 0; nf < 4; ++nf) {
        const int drow = nf * 16 + lrow;
        const int cirv = (ks * 4 + lgrp) ^ (drow & 7);
        const short8 vf = *reinterpret_cast<const short8*>(&lds_vt[drow * 64 + cirv * 8]);
        oacc[nf] = __builtin_amdgcn_mfma_f32_16x16x32_bf16(pf, vf, oacc[nf], 0, 0, 0);
      }
    }
  }

  // epilogue: O[b, t, h*64+d] = oacc / l
  float inv[4];
#pragma unroll
  for (int r = 0; r < 4; ++r) inv[r] = 1.0f / l_run[r];
#pragma unroll
  for (int nf = 0; nf < 4; ++nf) {
#pragma unroll
    for (int r = 0; r < 4; ++r) {
      const int t = qt * 64 + w * 16 + lgrp * 4 + r;
      O[base + (size_t)t * 1024 + nf * 16 + lrow] = f2bf(oacc[nf][r] * inv[r]);
    }
  }
}

// ---------------- launcher ----------------
extern "C" void kernel_launch(void* const* d_in, const int* in_sizes, int n_in,
                              void* d_out, int out_size, void* d_ws, size_t ws_size,
                              hipStream_t stream) {
  const float* x  = (const float*)d_in[0];
  const float* Wq = (const float*)d_in[1];
  const float* Wk = (const float*)d_in[2];
  const float* Wv = (const float*)d_in[3];
  const float* Wo = (const float*)d_in[4];

  uint8_t* ws = (uint8_t*)d_ws;
  short* xb  = (short*)(ws + 0);           // 8192x1024 bf16  (16 MiB)
  short* wqb = (short*)(ws + 16777216);    // 1024x1024 bf16  (2 MiB)
  short* wkb = (short*)(ws + 18874368);
  short* wvb = (short*)(ws + 20971520);
  short* wob = (short*)(ws + 23068672);
  short* Qb  = (short*)(ws + 25165824);    // 8192x1024 bf16
  short* Kb  = (short*)(ws + 41943040);
  short* Vb  = (short*)(ws + 58720256);
  short* Ob  = (short*)(ws + 75497472);
  if (ws_size < 92274688ull) return;  // fail loudly (output stays poisoned)

  cvt_f32_bf16<<<8192, 256, 0, stream>>>(x, xb, 2097152);
  cvt_f32_bf16<<<1024, 256, 0, stream>>>(Wq, wqb, 262144);
  cvt_f32_bf16<<<1024, 256, 0, stream>>>(Wk, wkb, 262144);
  cvt_f32_bf16<<<1024, 256, 0, stream>>>(Wv, wvb, 262144);
  cvt_f32_bf16<<<1024, 256, 0, stream>>>(Wo, wob, 262144);

  gemm_qkv<<<dim3(64, 8, 3), 256, 0, stream>>>(xb, wqb, wkb, wvb, Qb, Kb, Vb);
  attn_fwd<<<dim3(32, 64), 256, 0, stream>>>(Qb, Kb, Vb, Ob);
  gemm_out<<<dim3(64, 8), 256, 0, stream>>>(Ob, wob, (float*)d_out);
}

// Round 2
// 336.843 us; speedup vs baseline: 1.2293x; 1.2293x over previous
//
#include <hip/hip_runtime.h>
#include <hip/hip_bf16.h>
#include <stdint.h>

// B=4, T=2048, D_MODEL=1024, H=16, hd=64
// Q/K/V/O token-major layout: [B*T, 1024] with head h at cols h*64..h*64+63.

typedef __attribute__((ext_vector_type(8))) short short8;    // 8 x bf16 (4 VGPRs)
typedef __attribute__((ext_vector_type(4))) short short4v;
typedef __attribute__((ext_vector_type(4))) float floatx4;

#define LOG2E 1.4426950408889634f

__device__ __forceinline__ void gload_lds16(const void* g, void* l) {
  __builtin_amdgcn_global_load_lds(
      (const __attribute__((address_space(1))) void*)g,
      (__attribute__((address_space(3))) void*)l, 16, 0, 0);
}

__device__ __forceinline__ short f2bf(float f) {
  __hip_bfloat16 h = __float2bfloat16(f);
  return *reinterpret_cast<short*>(&h);
}

// ---------------- fp32 -> bf16 conversion ----------------
__global__ __launch_bounds__(256) void cvt_f32_bf16(const float* __restrict__ src,
                                                    short* __restrict__ dst, int n4) {
  const int i = blockIdx.x * blockDim.x + threadIdx.x;
  if (i >= n4) return;
  const float4 v = reinterpret_cast<const float4*>(src)[i];
  short4v o;
  o.x = f2bf(v.x); o.y = f2bf(v.y); o.z = f2bf(v.z); o.w = f2bf(v.w);
  reinterpret_cast<short4v*>(dst)[i] = o;
}

// ---------------- bf16 GEMM, C[m,n] = sum_k A[m,k]*B[n,k] ----------------
// 128x128 tile, BK=64, 256 threads (2x2 waves of 64x64), global_load_lds w=16,
// st-style XOR swizzle: logical 16B chunk c of row r lives at LDS chunk c^(r&7).
template <bool BF16OUT>
__device__ __forceinline__ void gemm_bt_body(const short* __restrict__ A,
                                             const short* __restrict__ B,
                                             void* __restrict__ Cout,
                                             int M, int N, int K, int m0, int n0) {
  __shared__ short lds_a[128 * 64];
  __shared__ short lds_b[128 * 64];
  const int tid = threadIdx.x;
  const int lane = tid & 63;
  const int w = tid >> 6;
  const int wm = w >> 1, wn = w & 1;
  const int lrow = lane & 15, lgrp = lane >> 4;

  floatx4 acc[4][4] = {};

  const int nkt = K >> 6;
  for (int kt = 0; kt < nkt; ++kt) {
    __syncthreads();
#pragma unroll
    for (int i = 0; i < 4; ++i) {  // stage A: 128 rows x 64 bf16 = 16KB
      const int chunk = i * 256 + tid;       // 0..1023
      const int row = chunk >> 3;            // 8 chunks per row
      const int cb = (chunk & 7) ^ (row & 7);  // inverse-swizzled source chunk
      gload_lds16(A + (size_t)(m0 + row) * K + kt * 64 + cb * 8, &lds_a[chunk * 8]);
    }
#pragma unroll
    for (int i = 0; i < 4; ++i) {  // stage B
      const int chunk = i * 256 + tid;
      const int row = chunk >> 3;
      const int cb = (chunk & 7) ^ (row & 7);
      gload_lds16(B + (size_t)(n0 + row) * K + kt * 64 + cb * 8, &lds_b[chunk * 8]);
    }
    __syncthreads();
#pragma unroll
    for (int ks = 0; ks < 2; ++ks) {
      short8 af[4], bfr[4];
#pragma unroll
      for (int mf = 0; mf < 4; ++mf) {
        const int row = wm * 64 + mf * 16 + lrow;
        const int cir = (ks * 4 + lgrp) ^ (row & 7);
        af[mf] = *reinterpret_cast<const short8*>(&lds_a[row * 64 + cir * 8]);
      }
#pragma unroll
      for (int nf = 0; nf < 4; ++nf) {
        const int row = wn * 64 + nf * 16 + lrow;
        const int cir = (ks * 4 + lgrp) ^ (row & 7);
        bfr[nf] = *reinterpret_cast<const short8*>(&lds_b[row * 64 + cir * 8]);
      }
#pragma unroll
      for (int mf = 0; mf < 4; ++mf)
#pragma unroll
        for (int nf = 0; nf < 4; ++nf)
          acc[mf][nf] =
              __builtin_amdgcn_mfma_f32_16x16x32_bf16(af[mf], bfr[nf], acc[mf][nf], 0, 0, 0);
    }
  }

  // epilogue: D row=(lane>>4)*4+r, col=lane&15 (verified m89/m91 mapping)
#pragma unroll
  for (int mf = 0; mf < 4; ++mf) {
#pragma unroll
    for (int nf = 0; nf < 4; ++nf) {
#pragma unroll
      for (int r = 0; r < 4; ++r) {
        const int grow = m0 + wm * 64 + mf * 16 + lgrp * 4 + r;
        const int gcol = n0 + wn * 64 + nf * 16 + lrow;
        if (BF16OUT)
          reinterpret_cast<short*>(Cout)[(size_t)grow * N + gcol] = f2bf(acc[mf][nf][r]);
        else
          reinterpret_cast<float*>(Cout)[(size_t)grow * N + gcol] = acc[mf][nf][r];
      }
    }
  }
}

__global__ __launch_bounds__(256) void gemm_qkv(
    const short* __restrict__ xb, const short* __restrict__ wq, const short* __restrict__ wk,
    const short* __restrict__ wv, short* __restrict__ Qb, short* __restrict__ Kb,
    short* __restrict__ Vb) {
  const short* Bm;
  short* Cm;
  if (blockIdx.z == 0) { Bm = wq; Cm = Qb; }
  else if (blockIdx.z == 1) { Bm = wk; Cm = Kb; }
  else { Bm = wv; Cm = Vb; }
  gemm_bt_body<true>(xb, Bm, Cm, 8192, 1024, 1024, blockIdx.x * 128, blockIdx.y * 128);
}

__global__ __launch_bounds__(256) void gemm_out(const short* __restrict__ Ob,
                                                const short* __restrict__ wo,
                                                float* __restrict__ out) {
  gemm_bt_body<false>(Ob, wo, out, 8192, 1024, 1024, blockIdx.x * 128, blockIdx.y * 128);
}

// ---------------- flash attention (causal), bf16 in/out ----------------
// grid (32 q-tiles, 64 b*h), 256 threads = 4 waves, each wave owns 16 q rows.
// 2-phase pipelined K/V staging: K via global_load_lds double-buffer (drained by
// the end-of-iteration barrier's implicit vmcnt(0)); V via global->reg issued
// early, ds_write late (T14). One barrier per KV tile.
__global__ __launch_bounds__(256, 4) void attn_fwd(const short* __restrict__ Q,
                                                   const short* __restrict__ K,
                                                   const short* __restrict__ V,
                                                   short* __restrict__ O) {
  __shared__ short lds_k[2][64 * 64];    // K tiles, swizzled, double-buffered
  __shared__ short lds_vt[2][64 * 64];   // V^T tiles, swizzled, double-buffered
  __shared__ short lds_p[4][16 * 64];    // per-wave P, swizzled

  const int tid = threadIdx.x;
  const int lane = tid & 63;
  const int w = tid >> 6;
  const int lrow = lane & 15, lgrp = lane >> 4;
  const int qt = blockIdx.x;
  const int bh = blockIdx.y;
  const int b = bh >> 4, h = bh & 15;

  const size_t base = (size_t)b * 2048 * 1024 + h * 64;

  // Q A-fragments hoisted to registers: lane holds Q[row=lrow][k=lgrp*8+j(+32*ks)]
  short8 qf[2];
  {
    const short* qp = Q + base + (size_t)(qt * 64 + w * 16 + lrow) * 1024 + lgrp * 8;
    qf[0] = *reinterpret_cast<const short8*>(qp);
    qf[1] = *reinterpret_cast<const short8*>(qp + 32);
  }

  floatx4 oacc[4] = {};
  float m_run[4], l_run[4];
#pragma unroll
  for (int r = 0; r < 4; ++r) { m_run[r] = -1e30f; l_run[r] = 0.f; }

  short8 vreg[2];

  // --- staging helpers (inlined lambdas) ---
  auto stageK = [&](int buf, int kb) {
#pragma unroll
    for (int i = 0; i < 2; ++i) {
      const int chunk = i * 256 + tid;   // 0..511
      const int row = chunk >> 3;
      const int cb = (chunk & 7) ^ (row & 7);
      gload_lds16(K + base + (size_t)(kb * 64 + row) * 1024 + cb * 8, &lds_k[buf][chunk * 8]);
    }
  };
  auto loadV = [&](int kb) {
#pragma unroll
    for (int i = 0; i < 2; ++i) {
      const int dseg = i * 4 + w;  // 0..7
      vreg[i] = *reinterpret_cast<const short8*>(
          V + base + (size_t)(kb * 64 + lane) * 1024 + dseg * 8);
    }
  };
  auto writeV = [&](int buf) {
#pragma unroll
    for (int i = 0; i < 2; ++i) {
      const int dseg = i * 4 + w;
#pragma unroll
      for (int j = 0; j < 8; ++j) {
        const int d = dseg * 8 + j;
        lds_vt[buf][d * 64 + ((((lane >> 3) ^ (d & 7)) << 3) | (lane & 7))] = vreg[i][j];
      }
    }
  };

  // --- prologue: stage tile 0 ---
  stageK(0, 0);
  loadV(0);
  writeV(0);
  __syncthreads();  // drains vmcnt(0): K tile 0 in LDS, V writes visible

  for (int kb = 0; kb <= qt; ++kb) {
    const int cur = kb & 1, nxt = cur ^ 1;

    // issue next tile's loads early (overlap with this tile's compute)
    if (kb < qt) {
      stageK(nxt, kb + 1);
      loadV(kb + 1);
    }

    // S = Q K^T : 16 q rows x 64 k cols per wave
    floatx4 s[4];
    __builtin_amdgcn_s_setprio(1);
#pragma unroll
    for (int nf = 0; nf < 4; ++nf) {
      floatx4 z = {};
#pragma unroll
      for (int ks = 0; ks < 2; ++ks) {
        const int row = nf * 16 + lrow;
        const int cir = (ks * 4 + lgrp) ^ (row & 7);
        const short8 kf = *reinterpret_cast<const short8*>(&lds_k[cur][row * 64 + cir * 8]);
        z = __builtin_amdgcn_mfma_f32_16x16x32_bf16(qf[ks], kf, z, 0, 0, 0);
      }
      s[nf] = z;
    }
    __builtin_amdgcn_s_setprio(0);

    // scale + causal mask + per-row max (rows of this lane's group: lgrp*4+r)
    const bool diag = (kb == qt);
    float vmax[4];
#pragma unroll
    for (int r = 0; r < 4; ++r) vmax[r] = -1e30f;
#pragma unroll
    for (int nf = 0; nf < 4; ++nf) {
#pragma unroll
      for (int r = 0; r < 4; ++r) {
        float xv = s[nf][r] * 0.125f;
        if (diag) {
          const int kcol = nf * 16 + lrow;            // local col (tile == diag tile)
          const int qrow = w * 16 + lgrp * 4 + r;     // local row
          if (kcol > qrow) xv = -1e30f;
        }
        s[nf][r] = xv;
        vmax[r] = fmaxf(vmax[r], xv);
      }
    }
#pragma unroll
    for (int d = 1; d < 16; d <<= 1)
#pragma unroll
      for (int r = 0; r < 4; ++r)
        vmax[r] = fmaxf(vmax[r], __shfl_xor(vmax[r], d, 64));

    float alpha[4], psum[4];
#pragma unroll
    for (int r = 0; r < 4; ++r) {
      const float mnew = fmaxf(m_run[r], vmax[r]);
      alpha[r] = exp2f((m_run[r] - mnew) * LOG2E);
      m_run[r] = mnew;
      psum[r] = 0.f;
    }

    // P = exp(S - m), write bf16 to per-wave LDS (swizzled), accumulate row sums
#pragma unroll
    for (int nf = 0; nf < 4; ++nf) {
#pragma unroll
      for (int r = 0; r < 4; ++r) {
        const float p = exp2f((s[nf][r] - m_run[r]) * LOG2E);
        psum[r] += p;
        const int prow = lgrp * 4 + r;
        const int pcol = nf * 16 + lrow;
        lds_p[w][prow * 64 + (((pcol >> 3) ^ (prow & 7)) << 3) + (pcol & 7)] = f2bf(p);
      }
    }
#pragma unroll
    for (int d = 1; d < 16; d <<= 1)
#pragma unroll
      for (int r = 0; r < 4; ++r) psum[r] += __shfl_xor(psum[r], d, 64);

#pragma unroll
    for (int r = 0; r < 4; ++r) l_run[r] = l_run[r] * alpha[r] + psum[r];

    // rescale O accumulator
#pragma unroll
    for (int nf = 0; nf < 4; ++nf)
#pragma unroll
      for (int r = 0; r < 4; ++r) oacc[nf][r] *= alpha[r];

    // O += P @ V   (A = P from lds_p, B = V^T from lds_vt)
    // lds_p is per-wave: no barrier needed, compiler inserts lgkmcnt for the RAW dep.
    __builtin_amdgcn_s_setprio(1);
#pragma unroll
    for (int ks = 0; ks < 2; ++ks) {
      const int cirp = (ks * 4 + lgrp) ^ (lrow & 7);
      const short8 pf = *reinterpret_cast<const short8*>(&lds_p[w][lrow * 64 + cirp * 8]);
#pragma unroll
      for (int nf = 0; nf < 4; ++nf) {
        const int drow = nf * 16 + lrow;
        const int cirv = (ks * 4 + lgrp) ^ (drow & 7);
        const short8 vf = *reinterpret_cast<const short8*>(&lds_vt[cur][drow * 64 + cirv * 8]);
        oacc[nf] = __builtin_amdgcn_mfma_f32_16x16x32_bf16(pf, vf, oacc[nf], 0, 0, 0);
      }
    }
    __builtin_amdgcn_s_setprio(0);

    // late half of V staging: vmcnt wait for vreg lands here (hidden by compute)
    if (kb < qt) writeV(nxt);

    __syncthreads();  // drains vmcnt(0) (K prefetch) + lgkmcnt (V writes)
  }

  // epilogue: O[b, t, h*64+d] = oacc / l
  float inv[4];
#pragma unroll
  for (int r = 0; r < 4; ++r) inv[r] = 1.0f / l_run[r];
#pragma unroll
  for (int nf = 0; nf < 4; ++nf) {
#pragma unroll
    for (int r = 0; r < 4; ++r) {
      const int t = qt * 64 + w * 16 + lgrp * 4 + r;
      O[base + (size_t)t * 1024 + nf * 16 + lrow] = f2bf(oacc[nf][r] * inv[r]);
    }
  }
}

// ---------------- launcher ----------------
extern "C" void kernel_launch(void* const* d_in, const int* in_sizes, int n_in,
                              void* d_out, int out_size, void* d_ws, size_t ws_size,
                              hipStream_t stream) {
  const float* x  = (const float*)d_in[0];
  const float* Wq = (const float*)d_in[1];
  const float* Wk = (const float*)d_in[2];
  const float* Wv = (const float*)d_in[3];
  const float* Wo = (const float*)d_in[4];

  uint8_t* ws = (uint8_t*)d_ws;
  short* xb  = (short*)(ws + 0);           // 8192x1024 bf16  (16 MiB)
  short* wqb = (short*)(ws + 16777216);    // 1024x1024 bf16  (2 MiB)
  short* wkb = (short*)(ws + 18874368);
  short* wvb = (short*)(ws + 20971520);
  short* wob = (short*)(ws + 23068672);
  short* Qb  = (short*)(ws + 25165824);    // 8192x1024 bf16
  short* Kb  = (short*)(ws + 41943040);
  short* Vb  = (short*)(ws + 58720256);
  short* Ob  = (short*)(ws + 75497472);
  if (ws_size < 92274688ull) return;  // fail loudly (output stays poisoned)

  cvt_f32_bf16<<<8192, 256, 0, stream>>>(x, xb, 2097152);
  cvt_f32_bf16<<<1024, 256, 0, stream>>>(Wq, wqb, 262144);
  cvt_f32_bf16<<<1024, 256, 0, stream>>>(Wk, wkb, 262144);
  cvt_f32_bf16<<<1024, 256, 0, stream>>>(Wv, wvb, 262144);
  cvt_f32_bf16<<<1024, 256, 0, stream>>>(Wo, wob, 262144);

  gemm_qkv<<<dim3(64, 8, 3), 256, 0, stream>>>(xb, wqb, wkb, wvb, Qb, Kb, Vb);
  attn_fwd<<<dim3(32, 64), 256, 0, stream>>>(Qb, Kb, Vb, Ob);
  gemm_out<<<dim3(64, 8), 256, 0, stream>>>(Ob, wob, (float*)d_out);
}

// Round 3
// 336.724 us; speedup vs baseline: 1.2297x; 1.0004x over previous
//
#include <hip/hip_runtime.h>
#include <hip/hip_bf16.h>
#include <stdint.h>

// B=4, T=2048, D_MODEL=1024, H=16, hd=64
// Q/K/V/O token-major layout: [B*T, 1024] with head h at cols h*64..h*64+63.

typedef __attribute__((ext_vector_type(8))) short short8;    // 8 x bf16 (4 VGPRs)
typedef __attribute__((ext_vector_type(4))) short short4v;
typedef __attribute__((ext_vector_type(4))) float floatx4;

#define LOG2E 1.4426950408889634f

__device__ __forceinline__ void gload_lds16(const void* g, void* l) {
  __builtin_amdgcn_global_load_lds(
      (const __attribute__((address_space(1))) void*)g,
      (__attribute__((address_space(3))) void*)l, 16, 0, 0);
}

__device__ __forceinline__ short f2bf(float f) {
  __hip_bfloat16 h = __float2bfloat16(f);
  return *reinterpret_cast<short*>(&h);
}

// ---------------- fp32 -> bf16 conversion ----------------
__global__ __launch_bounds__(256) void cvt_f32_bf16(const float* __restrict__ src,
                                                    short* __restrict__ dst, int n4) {
  const int i = blockIdx.x * blockDim.x + threadIdx.x;
  if (i >= n4) return;
  const float4 v = reinterpret_cast<const float4*>(src)[i];
  short4v o;
  o.x = f2bf(v.x); o.y = f2bf(v.y); o.z = f2bf(v.z); o.w = f2bf(v.w);
  reinterpret_cast<short4v*>(dst)[i] = o;
}

// ---------------- bf16 GEMM, C[m,n] = sum_k A[m,k]*B[n,k] ----------------
template <bool BF16OUT>
__device__ __forceinline__ void gemm_bt_body(const short* __restrict__ A,
                                             const short* __restrict__ B,
                                             void* __restrict__ Cout,
                                             int M, int N, int K, int m0, int n0) {
  __shared__ short lds_a[128 * 64];
  __shared__ short lds_b[128 * 64];
  const int tid = threadIdx.x;
  const int lane = tid & 63;
  const int w = tid >> 6;
  const int wm = w >> 1, wn = w & 1;
  const int lrow = lane & 15, lgrp = lane >> 4;

  floatx4 acc[4][4] = {};

  const int nkt = K >> 6;
  for (int kt = 0; kt < nkt; ++kt) {
    __syncthreads();
#pragma unroll
    for (int i = 0; i < 4; ++i) {
      const int chunk = i * 256 + tid;
      const int row = chunk >> 3;
      const int cb = (chunk & 7) ^ (row & 7);
      gload_lds16(A + (size_t)(m0 + row) * K + kt * 64 + cb * 8, &lds_a[chunk * 8]);
    }
#pragma unroll
    for (int i = 0; i < 4; ++i) {
      const int chunk = i * 256 + tid;
      const int row = chunk >> 3;
      const int cb = (chunk & 7) ^ (row & 7);
      gload_lds16(B + (size_t)(n0 + row) * K + kt * 64 + cb * 8, &lds_b[chunk * 8]);
    }
    __syncthreads();
#pragma unroll
    for (int ks = 0; ks < 2; ++ks) {
      short8 af[4], bfr[4];
#pragma unroll
      for (int mf = 0; mf < 4; ++mf) {
        const int row = wm * 64 + mf * 16 + lrow;
        const int cir = (ks * 4 + lgrp) ^ (row & 7);
        af[mf] = *reinterpret_cast<const short8*>(&lds_a[row * 64 + cir * 8]);
      }
#pragma unroll
      for (int nf = 0; nf < 4; ++nf) {
        const int row = wn * 64 + nf * 16 + lrow;
        const int cir = (ks * 4 + lgrp) ^ (row & 7);
        bfr[nf] = *reinterpret_cast<const short8*>(&lds_b[row * 64 + cir * 8]);
      }
#pragma unroll
      for (int mf = 0; mf < 4; ++mf)
#pragma unroll
        for (int nf = 0; nf < 4; ++nf)
          acc[mf][nf] =
              __builtin_amdgcn_mfma_f32_16x16x32_bf16(af[mf], bfr[nf], acc[mf][nf], 0, 0, 0);
    }
  }

#pragma unroll
  for (int mf = 0; mf < 4; ++mf) {
#pragma unroll
    for (int nf = 0; nf < 4; ++nf) {
#pragma unroll
      for (int r = 0; r < 4; ++r) {
        const int grow = m0 + wm * 64 + mf * 16 + lgrp * 4 + r;
        const int gcol = n0 + wn * 64 + nf * 16 + lrow;
        if (BF16OUT)
          reinterpret_cast<short*>(Cout)[(size_t)grow * N + gcol] = f2bf(acc[mf][nf][r]);
        else
          reinterpret_cast<float*>(Cout)[(size_t)grow * N + gcol] = acc[mf][nf][r];
      }
    }
  }
}

__global__ __launch_bounds__(256) void gemm_qkv(
    const short* __restrict__ xb, const short* __restrict__ wq, const short* __restrict__ wk,
    const short* __restrict__ wv, short* __restrict__ Qb, short* __restrict__ Kb,
    short* __restrict__ Vb) {
  const short* Bm;
  short* Cm;
  if (blockIdx.z == 0) { Bm = wq; Cm = Qb; }
  else if (blockIdx.z == 1) { Bm = wk; Cm = Kb; }
  else { Bm = wv; Cm = Vb; }
  gemm_bt_body<true>(xb, Bm, Cm, 8192, 1024, 1024, blockIdx.x * 128, blockIdx.y * 128);
}

__global__ __launch_bounds__(256) void gemm_out(const short* __restrict__ Ob,
                                                const short* __restrict__ wo,
                                                float* __restrict__ out) {
  gemm_bt_body<false>(Ob, wo, out, 8192, 1024, 1024, blockIdx.x * 128, blockIdx.y * 128);
}

// ---------------- flash attention (causal), bf16 in/out ----------------
// 512 threads = 8 waves; wave owns 32 q rows (2 x 16-row MFMA q-tiles).
// Block covers 256 q rows; grid (8 qc, 64 bh) = 512 blocks = 2/CU, all resident.
// Swapped QK^T: S^T = mfma(K_frag, Q_frag) -> lane holds k-slices for ONE q row
// (q = lane&15 of each q-tile). Softmax reduce = in-reg 16 + 2 shfl. P packed to
// LDS via b64 writes, read back as b128 A-frags for PV. K via global_load_lds
// double-buffer; V reg-staged (scatter-transposed) double-buffer.
__global__ __launch_bounds__(512, 4) void attn_fwd(const short* __restrict__ Q,
                                                   const short* __restrict__ K,
                                                   const short* __restrict__ V,
                                                   short* __restrict__ O) {
  __shared__ short lds_k[2][64 * 64];       // 16 KB
  __shared__ short lds_vt[2][64 * 64];      // 16 KB
  __shared__ short lds_p[8][2][16 * 64];    // 32 KB : [wave][qtile][16q][64k] swizzled

  const int tid = threadIdx.x;
  const int lane = tid & 63;
  const int w = tid >> 6;
  const int lrow = lane & 15, lgrp = lane >> 4;
  const int qc = 7 - blockIdx.x;            // heavy blocks first
  const int bh = blockIdx.y;
  const int b = bh >> 4, h = bh & 15;

  const size_t base = (size_t)b * 2048 * 1024 + h * 64;
  const int qw = qc * 256 + w * 32;         // wave's first q row
  const int lastkb = qw >> 6;               // last KV tile this wave participates in
  const int nkb = qc * 4 + 4;               // block KV-tile count

  // Q B-frags: qf[qt][ks] = Q[qw + qt*16 + lrow][ks*32 + lgrp*8 .. +8]
  short8 qf[2][2];
#pragma unroll
  for (int qt = 0; qt < 2; ++qt)
#pragma unroll
    for (int ks = 0; ks < 2; ++ks)
      qf[qt][ks] = *reinterpret_cast<const short8*>(
          Q + base + (size_t)(qw + qt * 16 + lrow) * 1024 + ks * 32 + lgrp * 8);

  floatx4 oacc[2][4] = {};
  float m_run[2], l_run[2];
#pragma unroll
  for (int qt = 0; qt < 2; ++qt) { m_run[qt] = -1e30f; l_run[qt] = 0.f; }

  short8 vreg;

  auto stageK = [&](int buf, int kb) {
    const int chunk = tid;                 // 512 chunks of 16B = 64x64 bf16
    const int row = chunk >> 3;
    const int cb = (chunk & 7) ^ (row & 7);
    gload_lds16(K + base + (size_t)(kb * 64 + row) * 1024 + cb * 8, &lds_k[buf][chunk * 8]);
  };
  auto loadV = [&](int kb) {
    const int k = tid & 63, dseg = tid >> 6;
    vreg = *reinterpret_cast<const short8*>(V + base + (size_t)(kb * 64 + k) * 1024 + dseg * 8);
  };
  auto writeV = [&](int buf) {
    const int k = tid & 63, dseg = tid >> 6;
#pragma unroll
    for (int j = 0; j < 8; ++j) {
      const int d = dseg * 8 + j;
      lds_vt[buf][d * 64 + ((((k >> 3) ^ (d & 7)) << 3) | (k & 7))] = vreg[j];
    }
  };

  // prologue
  stageK(0, 0);
  loadV(0);
  writeV(0);
  __syncthreads();

  for (int kb = 0; kb < nkb; ++kb) {
    const int cur = kb & 1, nxt = cur ^ 1;
    if (kb + 1 < nkb) { stageK(nxt, kb + 1); loadV(kb + 1); }

    if (kb <= lastkb) {
      // ---- S^T = mfma(K, Q): lane gets s[qt][nf][r] = S[q=qt*16+lrow][k=nf*16+lgrp*4+r]
      floatx4 s[2][4];
      __builtin_amdgcn_s_setprio(1);
#pragma unroll
      for (int nf = 0; nf < 4; ++nf) {
        const int krow = nf * 16 + lrow;
        const short8 kf0 = *reinterpret_cast<const short8*>(
            &lds_k[cur][krow * 64 + ((lgrp) ^ (krow & 7)) * 8]);
        const short8 kf1 = *reinterpret_cast<const short8*>(
            &lds_k[cur][krow * 64 + ((4 + lgrp) ^ (krow & 7)) * 8]);
#pragma unroll
        for (int qt = 0; qt < 2; ++qt) {
          floatx4 z = {};
          z = __builtin_amdgcn_mfma_f32_16x16x32_bf16(kf0, qf[qt][0], z, 0, 0, 0);
          z = __builtin_amdgcn_mfma_f32_16x16x32_bf16(kf1, qf[qt][1], z, 0, 0, 0);
          s[qt][nf] = z;
        }
      }
      __builtin_amdgcn_s_setprio(0);

      // ---- scale + causal mask + row max (row = q = qt*16+lrow, data across nf,r)
      const bool diag = (kb == lastkb);
      float vmax[2] = {-1e30f, -1e30f};
#pragma unroll
      for (int qt = 0; qt < 2; ++qt) {
#pragma unroll
        for (int nf = 0; nf < 4; ++nf) {
#pragma unroll
          for (int r = 0; r < 4; ++r) {
            float xv = s[qt][nf][r] * 0.125f;
            if (diag) {
              const int kg = kb * 64 + nf * 16 + lgrp * 4 + r;
              const int qg = qw + qt * 16 + lrow;
              if (kg > qg) xv = -1e30f;
            }
            s[qt][nf][r] = xv;
            vmax[qt] = fmaxf(vmax[qt], xv);
          }
        }
      }
#pragma unroll
      for (int qt = 0; qt < 2; ++qt) {
        vmax[qt] = fmaxf(vmax[qt], __shfl_xor(vmax[qt], 16, 64));
        vmax[qt] = fmaxf(vmax[qt], __shfl_xor(vmax[qt], 32, 64));
      }

      float alpha[2], psum[2];
#pragma unroll
      for (int qt = 0; qt < 2; ++qt) {
        const float mnew = fmaxf(m_run[qt], vmax[qt]);
        alpha[qt] = exp2f((m_run[qt] - mnew) * LOG2E);
        m_run[qt] = mnew;
        psum[qt] = 0.f;
      }

      // ---- P = exp(S-m): pack 4 consecutive k per nf -> one b64 LDS write
#pragma unroll
      for (int qt = 0; qt < 2; ++qt) {
#pragma unroll
        for (int nf = 0; nf < 4; ++nf) {
          float p0 = exp2f((s[qt][nf][0] - m_run[qt]) * LOG2E);
          float p1 = exp2f((s[qt][nf][1] - m_run[qt]) * LOG2E);
          float p2 = exp2f((s[qt][nf][2] - m_run[qt]) * LOG2E);
          float p3 = exp2f((s[qt][nf][3] - m_run[qt]) * LOG2E);
          psum[qt] += (p0 + p1) + (p2 + p3);
          short4v pk;
          pk.x = f2bf(p0); pk.y = f2bf(p1); pk.z = f2bf(p2); pk.w = f2bf(p3);
          const int c8 = (nf * 4 + lgrp) ^ ((lrow & 7) << 1);   // swizzled 8B chunk
          *reinterpret_cast<short4v*>(&lds_p[w][qt][lrow * 64 + c8 * 4]) = pk;
        }
      }
#pragma unroll
      for (int qt = 0; qt < 2; ++qt) {
        psum[qt] += __shfl_xor(psum[qt], 16, 64);
        psum[qt] += __shfl_xor(psum[qt], 32, 64);
        l_run[qt] = l_run[qt] * alpha[qt] + psum[qt];
      }

      // ---- rescale O accumulator (acc rows = q = lgrp*4+r -> fetch that row's alpha)
#pragma unroll
      for (int qt = 0; qt < 2; ++qt) {
#pragma unroll
        for (int r = 0; r < 4; ++r) {
          const float a = __shfl(alpha[qt], lgrp * 4 + r, 64);
#pragma unroll
          for (int nf = 0; nf < 4; ++nf) oacc[qt][nf][r] *= a;
        }
      }

      // ---- PV: A = P (from per-wave LDS), B = V^T
      short8 pa[2][2];
#pragma unroll
      for (int qt = 0; qt < 2; ++qt)
#pragma unroll
        for (int ks = 0; ks < 2; ++ks) {
          const int c16 = (ks * 4 + lgrp) ^ (lrow & 7);
          pa[qt][ks] = *reinterpret_cast<const short8*>(&lds_p[w][qt][lrow * 64 + c16 * 8]);
        }
      __builtin_amdgcn_s_setprio(1);
#pragma unroll
      for (int nf = 0; nf < 4; ++nf) {
        const int drow = nf * 16 + lrow;
        const short8 vf0 = *reinterpret_cast<const short8*>(
            &lds_vt[cur][drow * 64 + ((lgrp) ^ (drow & 7)) * 8]);
        const short8 vf1 = *reinterpret_cast<const short8*>(
            &lds_vt[cur][drow * 64 + ((4 + lgrp) ^ (drow & 7)) * 8]);
#pragma unroll
        for (int qt = 0; qt < 2; ++qt) {
          oacc[qt][nf] = __builtin_amdgcn_mfma_f32_16x16x32_bf16(pa[qt][0], vf0, oacc[qt][nf], 0, 0, 0);
          oacc[qt][nf] = __builtin_amdgcn_mfma_f32_16x16x32_bf16(pa[qt][1], vf1, oacc[qt][nf], 0, 0, 0);
        }
      }
      __builtin_amdgcn_s_setprio(0);
    }

    if (kb + 1 < nkb) writeV(nxt);
    __syncthreads();
  }

  // ---- epilogue: O rows = q = qw + qt*16 + lgrp*4 + r; divide by that row's l
#pragma unroll
  for (int qt = 0; qt < 2; ++qt) {
#pragma unroll
    for (int r = 0; r < 4; ++r) {
      const float linv = 1.0f / __shfl(l_run[qt], lgrp * 4 + r, 64);
      const int t = qw + qt * 16 + lgrp * 4 + r;
#pragma unroll
      for (int nf = 0; nf < 4; ++nf)
        O[base + (size_t)t * 1024 + nf * 16 + lrow] = f2bf(oacc[qt][nf][r] * linv);
    }
  }
}

// ---------------- launcher ----------------
extern "C" void kernel_launch(void* const* d_in, const int* in_sizes, int n_in,
                              void* d_out, int out_size, void* d_ws, size_t ws_size,
                              hipStream_t stream) {
  const float* x  = (const float*)d_in[0];
  const float* Wq = (const float*)d_in[1];
  const float* Wk = (const float*)d_in[2];
  const float* Wv = (const float*)d_in[3];
  const float* Wo = (const float*)d_in[4];

  uint8_t* ws = (uint8_t*)d_ws;
  short* xb  = (short*)(ws + 0);           // 8192x1024 bf16  (16 MiB)
  short* wqb = (short*)(ws + 16777216);    // 1024x1024 bf16  (2 MiB)
  short* wkb = (short*)(ws + 18874368);
  short* wvb = (short*)(ws + 20971520);
  short* wob = (short*)(ws + 23068672);
  short* Qb  = (short*)(ws + 25165824);    // 8192x1024 bf16
  short* Kb  = (short*)(ws + 41943040);
  short* Vb  = (short*)(ws + 58720256);
  short* Ob  = (short*)(ws + 75497472);
  if (ws_size < 92274688ull) return;  // fail loudly (output stays poisoned)

  cvt_f32_bf16<<<8192, 256, 0, stream>>>(x, xb, 2097152);
  cvt_f32_bf16<<<1024, 256, 0, stream>>>(Wq, wqb, 262144);
  cvt_f32_bf16<<<1024, 256, 0, stream>>>(Wk, wkb, 262144);
  cvt_f32_bf16<<<1024, 256, 0, stream>>>(Wv, wvb, 262144);
  cvt_f32_bf16<<<1024, 256, 0, stream>>>(Wo, wob, 262144);

  gemm_qkv<<<dim3(64, 8, 3), 256, 0, stream>>>(xb, wqb, wkb, wvb, Qb, Kb, Vb);
  attn_fwd<<<dim3(8, 64), 512, 0, stream>>>(Qb, Kb, Vb, Ob);
  gemm_out<<<dim3(64, 8), 256, 0, stream>>>(Ob, wob, (float*)d_out);
}

// Round 4
// 217.248 us; speedup vs baseline: 1.9060x; 1.5500x over previous
//
#include <hip/hip_runtime.h>
#include <hip/hip_bf16.h>
#include <stdint.h>

// B=4, T=2048, D_MODEL=1024, H=16, hd=64
// Q/K token-major: [B*T, 1024], head h at cols h*64..h*64+63.
// V is stored TRANSPOSED: Vt[bh][d][t] = Vt[bh*131072 + d*2048 + t] (bf16).

typedef __attribute__((ext_vector_type(8))) short short8;    // 8 x bf16 (4 VGPRs)
typedef __attribute__((ext_vector_type(4))) short short4v;
typedef __attribute__((ext_vector_type(4))) float floatx4;

#define LOG2E 1.4426950408889634f

__device__ __forceinline__ void gload_lds16(const void* g, void* l) {
  __builtin_amdgcn_global_load_lds(
      (const __attribute__((address_space(1))) void*)g,
      (__attribute__((address_space(3))) void*)l, 16, 0, 0);
}

__device__ __forceinline__ short f2bf(float f) {
  __hip_bfloat16 h = __float2bfloat16(f);
  return *reinterpret_cast<short*>(&h);
}

// ---------------- fp32 -> bf16 conversion ----------------
__global__ __launch_bounds__(256) void cvt_f32_bf16(const float* __restrict__ src,
                                                    short* __restrict__ dst, int n4) {
  const int i = blockIdx.x * blockDim.x + threadIdx.x;
  if (i >= n4) return;
  const float4 v = reinterpret_cast<const float4*>(src)[i];
  short4v o;
  o.x = f2bf(v.x); o.y = f2bf(v.y); o.z = f2bf(v.z); o.w = f2bf(v.w);
  reinterpret_cast<short4v*>(dst)[i] = o;
}

// ---------------- bf16 GEMM, C[m,n] = sum_k A[m,k]*B[n,k] ----------------
// MODE 0: f32 row-major out. MODE 1: bf16 row-major out.
// MODE 2: bf16 out transposed per-head -> Vt[bh][d][t] (b64 packed stores).
template <int MODE>
__device__ __forceinline__ void gemm_bt_body(const short* __restrict__ A,
                                             const short* __restrict__ B,
                                             void* __restrict__ Cout,
                                             int M, int N, int K, int m0, int n0) {
  __shared__ short lds_a[128 * 64];
  __shared__ short lds_b[128 * 64];
  const int tid = threadIdx.x;
  const int lane = tid & 63;
  const int w = tid >> 6;
  const int wm = w >> 1, wn = w & 1;
  const int lrow = lane & 15, lgrp = lane >> 4;

  floatx4 acc[4][4] = {};

  const int nkt = K >> 6;
  for (int kt = 0; kt < nkt; ++kt) {
    __syncthreads();
#pragma unroll
    for (int i = 0; i < 4; ++i) {
      const int chunk = i * 256 + tid;
      const int row = chunk >> 3;
      const int cb = (chunk & 7) ^ (row & 7);
      gload_lds16(A + (size_t)(m0 + row) * K + kt * 64 + cb * 8, &lds_a[chunk * 8]);
    }
#pragma unroll
    for (int i = 0; i < 4; ++i) {
      const int chunk = i * 256 + tid;
      const int row = chunk >> 3;
      const int cb = (chunk & 7) ^ (row & 7);
      gload_lds16(B + (size_t)(n0 + row) * K + kt * 64 + cb * 8, &lds_b[chunk * 8]);
    }
    __syncthreads();
#pragma unroll
    for (int ks = 0; ks < 2; ++ks) {
      short8 af[4], bfr[4];
#pragma unroll
      for (int mf = 0; mf < 4; ++mf) {
        const int row = wm * 64 + mf * 16 + lrow;
        const int cir = (ks * 4 + lgrp) ^ (row & 7);
        af[mf] = *reinterpret_cast<const short8*>(&lds_a[row * 64 + cir * 8]);
      }
#pragma unroll
      for (int nf = 0; nf < 4; ++nf) {
        const int row = wn * 64 + nf * 16 + lrow;
        const int cir = (ks * 4 + lgrp) ^ (row & 7);
        bfr[nf] = *reinterpret_cast<const short8*>(&lds_b[row * 64 + cir * 8]);
      }
#pragma unroll
      for (int mf = 0; mf < 4; ++mf)
#pragma unroll
        for (int nf = 0; nf < 4; ++nf)
          acc[mf][nf] =
              __builtin_amdgcn_mfma_f32_16x16x32_bf16(af[mf], bfr[nf], acc[mf][nf], 0, 0, 0);
    }
  }

#pragma unroll
  for (int mf = 0; mf < 4; ++mf) {
#pragma unroll
    for (int nf = 0; nf < 4; ++nf) {
      if (MODE == 2) {
        // lane holds 4 consecutive tokens (rows) of one channel (col): free transpose.
        short4v pk;
#pragma unroll
        for (int r = 0; r < 4; ++r) pk[r] = f2bf(acc[mf][nf][r]);
        const int t0 = m0 + wm * 64 + mf * 16 + lgrp * 4;  // token (4 consecutive)
        const int ch = n0 + wn * 64 + nf * 16 + lrow;      // channel
        const int bh = ((t0 >> 11) << 4) + (ch >> 6);
        short* Vt = reinterpret_cast<short*>(Cout);
        *reinterpret_cast<short4v*>(
            &Vt[(size_t)bh * 131072 + (size_t)(ch & 63) * 2048 + (t0 & 2047)]) = pk;
      } else {
#pragma unroll
        for (int r = 0; r < 4; ++r) {
          const int grow = m0 + wm * 64 + mf * 16 + lgrp * 4 + r;
          const int gcol = n0 + wn * 64 + nf * 16 + lrow;
          if (MODE == 1)
            reinterpret_cast<short*>(Cout)[(size_t)grow * N + gcol] = f2bf(acc[mf][nf][r]);
          else
            reinterpret_cast<float*>(Cout)[(size_t)grow * N + gcol] = acc[mf][nf][r];
        }
      }
    }
  }
}

__global__ __launch_bounds__(256) void gemm_qk(
    const short* __restrict__ xb, const short* __restrict__ wq, const short* __restrict__ wk,
    short* __restrict__ Qb, short* __restrict__ Kb) {
  const short* Bm = (blockIdx.z == 0) ? wq : wk;
  short* Cm = (blockIdx.z == 0) ? Qb : Kb;
  gemm_bt_body<1>(xb, Bm, Cm, 8192, 1024, 1024, blockIdx.x * 128, blockIdx.y * 128);
}

__global__ __launch_bounds__(256) void gemm_v(const short* __restrict__ xb,
                                              const short* __restrict__ wv,
                                              short* __restrict__ Vt) {
  gemm_bt_body<2>(xb, wv, Vt, 8192, 1024, 1024, blockIdx.x * 128, blockIdx.y * 128);
}

__global__ __launch_bounds__(256) void gemm_out(const short* __restrict__ Ob,
                                                const short* __restrict__ wo,
                                                float* __restrict__ out) {
  gemm_bt_body<0>(Ob, wo, out, 8192, 1024, 1024, blockIdx.x * 128, blockIdx.y * 128);
}

// ---------------- flash attention (causal), bf16 in/out ----------------
// 512 threads = 8 waves; wave owns 32 q rows (2 x 16-row MFMA q-tiles) per pass.
// Each block processes TWO 256-row q-chunks: (7-p) then (p) -> exactly 36 KV-tile
// iterations for every block (perfect balance). Grid (4, 64) = 256 blocks = 1/CU.
// K staged row-major [k][dim], V staged from pre-transposed Vt as [d][k]; both via
// global_load_lds double-buffer with XOR chunk swizzle. Swapped QK^T (S^T =
// mfma(K,Q)); P packed b64 -> per-wave LDS -> b128 A-frags for PV.
__global__ __launch_bounds__(512, 2) void attn_fwd(const short* __restrict__ Q,
                                                   const short* __restrict__ K,
                                                   const short* __restrict__ Vt,
                                                   short* __restrict__ O) {
  __shared__ short lds_k[2][64 * 64];       // 16 KB
  __shared__ short lds_v[2][64 * 64];       // 16 KB : [d][k] swizzled
  __shared__ short lds_p[8][2][16 * 64];    // 32 KB : [wave][qtile][16q][64k] swizzled

  const int tid = threadIdx.x;
  const int lane = tid & 63;
  const int w = tid >> 6;
  const int lrow = lane & 15, lgrp = lane >> 4;
  const int p = blockIdx.x;                 // 0..3, chunk pair (7-p, p)
  const int bh = blockIdx.y;
  const int b = bh >> 4, h = bh & 15;

  const size_t base = (size_t)b * 2048 * 1024 + h * 64;
  const size_t vbase = (size_t)bh * 131072;

  auto stageK = [&](int buf, int kb) {
    const int chunk = tid;                  // 512 chunks of 16B = 64x64 bf16
    const int row = chunk >> 3;
    const int cb = (chunk & 7) ^ (row & 7);
    gload_lds16(K + base + (size_t)(kb * 64 + row) * 1024 + cb * 8, &lds_k[buf][chunk * 8]);
  };
  auto stageV = [&](int buf, int kb) {
    const int chunk = tid;
    const int d = chunk >> 3;
    const int cb = (chunk & 7) ^ (d & 7);
    gload_lds16(Vt + vbase + (size_t)d * 2048 + kb * 64 + cb * 8, &lds_v[buf][chunk * 8]);
  };

#pragma unroll 1
  for (int pass = 0; pass < 2; ++pass) {
    const int qc = pass == 0 ? (7 - p) : p;
    const int qw = qc * 256 + w * 32;       // wave's first q row
    const int lastkb = qw >> 6;             // last KV tile this wave participates in
    const int nkb = qc * 4 + 4;             // chunk KV-tile count

    // Q B-frags: qf[qt][ks] = Q[qw + qt*16 + lrow][ks*32 + lgrp*8 .. +8]
    short8 qf[2][2];
#pragma unroll
    for (int qt = 0; qt < 2; ++qt)
#pragma unroll
      for (int ks = 0; ks < 2; ++ks)
        qf[qt][ks] = *reinterpret_cast<const short8*>(
            Q + base + (size_t)(qw + qt * 16 + lrow) * 1024 + ks * 32 + lgrp * 8);

    floatx4 oacc[2][4] = {};
    float m_run[2], l_run[2];
#pragma unroll
    for (int qt = 0; qt < 2; ++qt) { m_run[qt] = -1e30f; l_run[qt] = 0.f; }

    // prologue: stage tile 0 (previous pass's final barrier protects buffer reuse)
    stageK(0, 0);
    stageV(0, 0);
    __syncthreads();

    for (int kb = 0; kb < nkb; ++kb) {
      const int cur = kb & 1, nxt = cur ^ 1;
      if (kb + 1 < nkb) { stageK(nxt, kb + 1); stageV(nxt, kb + 1); }

      if (kb <= lastkb) {
        // ---- S^T = mfma(K, Q): s[qt][nf][r] = S[q=qt*16+lrow][k=nf*16+lgrp*4+r]
        floatx4 s[2][4];
        __builtin_amdgcn_s_setprio(1);
#pragma unroll
        for (int nf = 0; nf < 4; ++nf) {
          const int krow = nf * 16 + lrow;
          const short8 kf0 = *reinterpret_cast<const short8*>(
              &lds_k[cur][krow * 64 + ((lgrp) ^ (krow & 7)) * 8]);
          const short8 kf1 = *reinterpret_cast<const short8*>(
              &lds_k[cur][krow * 64 + ((4 + lgrp) ^ (krow & 7)) * 8]);
#pragma unroll
          for (int qt = 0; qt < 2; ++qt) {
            floatx4 z = {};
            z = __builtin_amdgcn_mfma_f32_16x16x32_bf16(kf0, qf[qt][0], z, 0, 0, 0);
            z = __builtin_amdgcn_mfma_f32_16x16x32_bf16(kf1, qf[qt][1], z, 0, 0, 0);
            s[qt][nf] = z;
          }
        }
        __builtin_amdgcn_s_setprio(0);

        // ---- scale + causal mask + row max
        const bool diag = (kb == lastkb);
        float vmax[2] = {-1e30f, -1e30f};
#pragma unroll
        for (int qt = 0; qt < 2; ++qt) {
#pragma unroll
          for (int nf = 0; nf < 4; ++nf) {
#pragma unroll
            for (int r = 0; r < 4; ++r) {
              float xv = s[qt][nf][r] * 0.125f;
              if (diag) {
                const int kg = kb * 64 + nf * 16 + lgrp * 4 + r;
                const int qg = qw + qt * 16 + lrow;
                if (kg > qg) xv = -1e30f;
              }
              s[qt][nf][r] = xv;
              vmax[qt] = fmaxf(vmax[qt], xv);
            }
          }
        }
#pragma unroll
        for (int qt = 0; qt < 2; ++qt) {
          vmax[qt] = fmaxf(vmax[qt], __shfl_xor(vmax[qt], 16, 64));
          vmax[qt] = fmaxf(vmax[qt], __shfl_xor(vmax[qt], 32, 64));
        }

        float alpha[2], psum[2];
#pragma unroll
        for (int qt = 0; qt < 2; ++qt) {
          const float mnew = fmaxf(m_run[qt], vmax[qt]);
          alpha[qt] = exp2f((m_run[qt] - mnew) * LOG2E);
          m_run[qt] = mnew;
          psum[qt] = 0.f;
        }

        // ---- P = exp(S-m): pack 4 consecutive k per nf -> one b64 LDS write
#pragma unroll
        for (int qt = 0; qt < 2; ++qt) {
#pragma unroll
          for (int nf = 0; nf < 4; ++nf) {
            float p0 = exp2f((s[qt][nf][0] - m_run[qt]) * LOG2E);
            float p1 = exp2f((s[qt][nf][1] - m_run[qt]) * LOG2E);
            float p2 = exp2f((s[qt][nf][2] - m_run[qt]) * LOG2E);
            float p3 = exp2f((s[qt][nf][3] - m_run[qt]) * LOG2E);
            psum[qt] += (p0 + p1) + (p2 + p3);
            short4v pk;
            pk.x = f2bf(p0); pk.y = f2bf(p1); pk.z = f2bf(p2); pk.w = f2bf(p3);
            const int c8 = (nf * 4 + lgrp) ^ ((lrow & 7) << 1);
            *reinterpret_cast<short4v*>(&lds_p[w][qt][lrow * 64 + c8 * 4]) = pk;
          }
        }
#pragma unroll
        for (int qt = 0; qt < 2; ++qt) {
          psum[qt] += __shfl_xor(psum[qt], 16, 64);
          psum[qt] += __shfl_xor(psum[qt], 32, 64);
          l_run[qt] = l_run[qt] * alpha[qt] + psum[qt];
        }

        // ---- rescale O accumulator (acc rows = q = lgrp*4+r)
#pragma unroll
        for (int qt = 0; qt < 2; ++qt) {
#pragma unroll
          for (int r = 0; r < 4; ++r) {
            const float a = __shfl(alpha[qt], lgrp * 4 + r, 64);
#pragma unroll
            for (int nf = 0; nf < 4; ++nf) oacc[qt][nf][r] *= a;
          }
        }

        // ---- PV: A = P (per-wave LDS), B-frag = V^T rows from lds_v [d][k]
        short8 pa[2][2];
#pragma unroll
        for (int qt = 0; qt < 2; ++qt)
#pragma unroll
          for (int ks = 0; ks < 2; ++ks) {
            const int c16 = (ks * 4 + lgrp) ^ (lrow & 7);
            pa[qt][ks] = *reinterpret_cast<const short8*>(&lds_p[w][qt][lrow * 64 + c16 * 8]);
          }
        __builtin_amdgcn_s_setprio(1);
#pragma unroll
        for (int nf = 0; nf < 4; ++nf) {
          const int drow = nf * 16 + lrow;
          const short8 vf0 = *reinterpret_cast<const short8*>(
              &lds_v[cur][drow * 64 + ((lgrp) ^ (drow & 7)) * 8]);
          const short8 vf1 = *reinterpret_cast<const short8*>(
              &lds_v[cur][drow * 64 + ((4 + lgrp) ^ (drow & 7)) * 8]);
#pragma unroll
          for (int qt = 0; qt < 2; ++qt) {
            oacc[qt][nf] = __builtin_amdgcn_mfma_f32_16x16x32_bf16(pa[qt][0], vf0, oacc[qt][nf], 0, 0, 0);
            oacc[qt][nf] = __builtin_amdgcn_mfma_f32_16x16x32_bf16(pa[qt][1], vf1, oacc[qt][nf], 0, 0, 0);
          }
        }
        __builtin_amdgcn_s_setprio(0);
      }

      __syncthreads();
    }

    // ---- epilogue: O rows = q = qw + qt*16 + lgrp*4 + r
#pragma unroll
    for (int qt = 0; qt < 2; ++qt) {
#pragma unroll
      for (int r = 0; r < 4; ++r) {
        const float linv = 1.0f / __shfl(l_run[qt], lgrp * 4 + r, 64);
        const int t = qw + qt * 16 + lgrp * 4 + r;
#pragma unroll
        for (int nf = 0; nf < 4; ++nf)
          O[base + (size_t)t * 1024 + nf * 16 + lrow] = f2bf(oacc[qt][nf][r] * linv);
      }
    }
  }
}

// ---------------- launcher ----------------
extern "C" void kernel_launch(void* const* d_in, const int* in_sizes, int n_in,
                              void* d_out, int out_size, void* d_ws, size_t ws_size,
                              hipStream_t stream) {
  const float* x  = (const float*)d_in[0];
  const float* Wq = (const float*)d_in[1];
  const float* Wk = (const float*)d_in[2];
  const float* Wv = (const float*)d_in[3];
  const float* Wo = (const float*)d_in[4];

  uint8_t* ws = (uint8_t*)d_ws;
  short* xb  = (short*)(ws + 0);           // 8192x1024 bf16  (16 MiB)
  short* wqb = (short*)(ws + 16777216);    // 1024x1024 bf16  (2 MiB)
  short* wkb = (short*)(ws + 18874368);
  short* wvb = (short*)(ws + 20971520);
  short* wob = (short*)(ws + 23068672);
  short* Qb  = (short*)(ws + 25165824);    // 8192x1024 bf16
  short* Kb  = (short*)(ws + 41943040);
  short* Vt  = (short*)(ws + 58720256);    // [64 bh][64 d][2048 t] bf16
  short* Ob  = (short*)(ws + 75497472);
  if (ws_size < 92274688ull) return;  // fail loudly (output stays poisoned)

  cvt_f32_bf16<<<8192, 256, 0, stream>>>(x, xb, 2097152);
  cvt_f32_bf16<<<1024, 256, 0, stream>>>(Wq, wqb, 262144);
  cvt_f32_bf16<<<1024, 256, 0, stream>>>(Wk, wkb, 262144);
  cvt_f32_bf16<<<1024, 256, 0, stream>>>(Wv, wvb, 262144);
  cvt_f32_bf16<<<1024, 256, 0, stream>>>(Wo, wob, 262144);

  gemm_qk<<<dim3(64, 8, 2), 256, 0, stream>>>(xb, wqb, wkb, Qb, Kb);
  gemm_v<<<dim3(64, 8), 256, 0, stream>>>(xb, wvb, Vt);
  attn_fwd<<<dim3(4, 64), 512, 0, stream>>>(Qb, Kb, Vt, Ob);
  gemm_out<<<dim3(64, 8), 256, 0, stream>>>(Ob, wob, (float*)d_out);
}

// Round 5
// 188.475 us; speedup vs baseline: 2.1969x; 1.1527x over previous
//
#include <hip/hip_runtime.h>
#include <hip/hip_bf16.h>
#include <stdint.h>

// B=4, T=2048, D_MODEL=1024, H=16, hd=64
// Q/K token-major: [B*T, 1024], head h at cols h*64..h*64+63.
// V is stored TRANSPOSED: Vt[bh][d][t] = Vt[bh*131072 + d*2048 + t] (bf16).
// W_Q is pre-scaled by 0.125*log2(e) so softmax runs in log2 domain.

typedef __attribute__((ext_vector_type(8))) short short8;    // 8 x bf16 (4 VGPRs)
typedef __attribute__((ext_vector_type(4))) short short4v;
typedef __attribute__((ext_vector_type(4))) float floatx4;

#define LOG2E 1.4426950408889634f

__device__ __forceinline__ void gload_lds16(const void* g, void* l) {
  __builtin_amdgcn_global_load_lds(
      (const __attribute__((address_space(1))) void*)g,
      (__attribute__((address_space(3))) void*)l, 16, 0, 0);
}

__device__ __forceinline__ short f2bf(float f) {
  __hip_bfloat16 h = __float2bfloat16(f);
  return *reinterpret_cast<short*>(&h);
}

// ---------------- fp32 -> bf16 conversion (optional scale) ----------------
__global__ __launch_bounds__(256) void cvt_f32_bf16(const float* __restrict__ src,
                                                    short* __restrict__ dst, int n4,
                                                    float scale) {
  const int i = blockIdx.x * blockDim.x + threadIdx.x;
  if (i >= n4) return;
  const float4 v = reinterpret_cast<const float4*>(src)[i];
  short4v o;
  o.x = f2bf(v.x * scale); o.y = f2bf(v.y * scale);
  o.z = f2bf(v.z * scale); o.w = f2bf(v.w * scale);
  reinterpret_cast<short4v*>(dst)[i] = o;
}

// ---------------- bf16 GEMM, C[m,n] = sum_k A[m,k]*B[n,k] ----------------
// MODE 0: f32 row-major out. MODE 1: bf16 row-major out.
// MODE 2: bf16 out transposed per-head -> Vt[bh][d][t] (b64 packed stores).
template <int MODE>
__device__ __forceinline__ void gemm_bt_body(const short* __restrict__ A,
                                             const short* __restrict__ B,
                                             void* __restrict__ Cout,
                                             int M, int N, int K, int m0, int n0) {
  __shared__ short lds_a[128 * 64];
  __shared__ short lds_b[128 * 64];
  const int tid = threadIdx.x;
  const int lane = tid & 63;
  const int w = tid >> 6;
  const int wm = w >> 1, wn = w & 1;
  const int lrow = lane & 15, lgrp = lane >> 4;

  floatx4 acc[4][4] = {};

  const int nkt = K >> 6;
  for (int kt = 0; kt < nkt; ++kt) {
    __syncthreads();
#pragma unroll
    for (int i = 0; i < 4; ++i) {
      const int chunk = i * 256 + tid;
      const int row = chunk >> 3;
      const int cb = (chunk & 7) ^ (row & 7);
      gload_lds16(A + (size_t)(m0 + row) * K + kt * 64 + cb * 8, &lds_a[chunk * 8]);
    }
#pragma unroll
    for (int i = 0; i < 4; ++i) {
      const int chunk = i * 256 + tid;
      const int row = chunk >> 3;
      const int cb = (chunk & 7) ^ (row & 7);
      gload_lds16(B + (size_t)(n0 + row) * K + kt * 64 + cb * 8, &lds_b[chunk * 8]);
    }
    __syncthreads();
#pragma unroll
    for (int ks = 0; ks < 2; ++ks) {
      short8 af[4], bfr[4];
#pragma unroll
      for (int mf = 0; mf < 4; ++mf) {
        const int row = wm * 64 + mf * 16 + lrow;
        const int cir = (ks * 4 + lgrp) ^ (row & 7);
        af[mf] = *reinterpret_cast<const short8*>(&lds_a[row * 64 + cir * 8]);
      }
#pragma unroll
      for (int nf = 0; nf < 4; ++nf) {
        const int row = wn * 64 + nf * 16 + lrow;
        const int cir = (ks * 4 + lgrp) ^ (row & 7);
        bfr[nf] = *reinterpret_cast<const short8*>(&lds_b[row * 64 + cir * 8]);
      }
#pragma unroll
      for (int mf = 0; mf < 4; ++mf)
#pragma unroll
        for (int nf = 0; nf < 4; ++nf)
          acc[mf][nf] =
              __builtin_amdgcn_mfma_f32_16x16x32_bf16(af[mf], bfr[nf], acc[mf][nf], 0, 0, 0);
    }
  }

#pragma unroll
  for (int mf = 0; mf < 4; ++mf) {
#pragma unroll
    for (int nf = 0; nf < 4; ++nf) {
      if (MODE == 2) {
        // lane holds 4 consecutive tokens (rows) of one channel (col): free transpose.
        short4v pk;
#pragma unroll
        for (int r = 0; r < 4; ++r) pk[r] = f2bf(acc[mf][nf][r]);
        const int t0 = m0 + wm * 64 + mf * 16 + lgrp * 4;  // token (4 consecutive)
        const int ch = n0 + wn * 64 + nf * 16 + lrow;      // channel
        const int bh = ((t0 >> 11) << 4) + (ch >> 6);
        short* Vt = reinterpret_cast<short*>(Cout);
        *reinterpret_cast<short4v*>(
            &Vt[(size_t)bh * 131072 + (size_t)(ch & 63) * 2048 + (t0 & 2047)]) = pk;
      } else {
#pragma unroll
        for (int r = 0; r < 4; ++r) {
          const int grow = m0 + wm * 64 + mf * 16 + lgrp * 4 + r;
          const int gcol = n0 + wn * 64 + nf * 16 + lrow;
          if (MODE == 1)
            reinterpret_cast<short*>(Cout)[(size_t)grow * N + gcol] = f2bf(acc[mf][nf][r]);
          else
            reinterpret_cast<float*>(Cout)[(size_t)grow * N + gcol] = acc[mf][nf][r];
        }
      }
    }
  }
}

__global__ __launch_bounds__(256) void gemm_qkv(
    const short* __restrict__ xb, const short* __restrict__ wq, const short* __restrict__ wk,
    const short* __restrict__ wv, short* __restrict__ Qb, short* __restrict__ Kb,
    short* __restrict__ Vt) {
  if (blockIdx.z == 0)
    gemm_bt_body<1>(xb, wq, Qb, 8192, 1024, 1024, blockIdx.x * 128, blockIdx.y * 128);
  else if (blockIdx.z == 1)
    gemm_bt_body<1>(xb, wk, Kb, 8192, 1024, 1024, blockIdx.x * 128, blockIdx.y * 128);
  else
    gemm_bt_body<2>(xb, wv, Vt, 8192, 1024, 1024, blockIdx.x * 128, blockIdx.y * 128);
}

__global__ __launch_bounds__(256) void gemm_out(const short* __restrict__ Ob,
                                                const short* __restrict__ wo,
                                                float* __restrict__ out) {
  gemm_bt_body<0>(Ob, wo, out, 8192, 1024, 1024, blockIdx.x * 128, blockIdx.y * 128);
}

// ---------------- flash attention (causal), bf16 in/out ----------------
// 512 threads = 8 waves; wave owns ONE 16-row q-tile; block covers 128 q rows.
// 16 q-chunks of 128 rows; block p processes chunk (15-p) then chunk p ->
// exactly 36 KV-tile iterations per block. Grid (8,64) = 512 blocks = 2/CU.
// Swapped QK^T in log2 domain (W_Q pre-scaled by 0.125*log2e); defer-max
// online softmax (THR=8 -> P <= 256); P via per-wave LDS b64/b128 round-trip.
__global__ __launch_bounds__(512, 4) void attn_fwd(const short* __restrict__ Q,
                                                   const short* __restrict__ K,
                                                   const short* __restrict__ Vt,
                                                   short* __restrict__ O) {
  __shared__ short lds_k[2][64 * 64];    // 16 KB
  __shared__ short lds_v[2][64 * 64];    // 16 KB : [d][k] swizzled
  __shared__ short lds_p[8][16 * 64];    // 16 KB : [wave][16q][64k] swizzled

  const int tid = threadIdx.x;
  const int lane = tid & 63;
  const int w = tid >> 6;
  const int lrow = lane & 15, lgrp = lane >> 4;
  const int p = blockIdx.x;              // 0..7 -> chunk pair (15-p, p)
  const int bh = blockIdx.y;
  const int b = bh >> 4, h = bh & 15;

  const size_t base = (size_t)b * 2048 * 1024 + h * 64;
  const size_t vbase = (size_t)bh * 131072;

  auto stageK = [&](int buf, int kb) {
    const int chunk = tid;               // 512 chunks of 16B = 64x64 bf16
    const int row = chunk >> 3;
    const int cb = (chunk & 7) ^ (row & 7);
    gload_lds16(K + base + (size_t)(kb * 64 + row) * 1024 + cb * 8, &lds_k[buf][chunk * 8]);
  };
  auto stageV = [&](int buf, int kb) {
    const int chunk = tid;
    const int d = chunk >> 3;
    const int cb = (chunk & 7) ^ (d & 7);
    gload_lds16(Vt + vbase + (size_t)d * 2048 + kb * 64 + cb * 8, &lds_v[buf][chunk * 8]);
  };

#pragma unroll 1
  for (int pass = 0; pass < 2; ++pass) {
    const int qc = pass == 0 ? (15 - p) : p;
    const int qw = qc * 128 + w * 16;    // wave's first q row
    const int lastkb = qw >> 6;          // last KV tile this wave participates in
    const int nkb = qc * 2 + 2;          // chunk KV-tile count

    // Q B-frags: qf[ks] = Q[qw + lrow][ks*32 + lgrp*8 .. +8]  (log2-prescaled)
    short8 qf[2];
#pragma unroll
    for (int ks = 0; ks < 2; ++ks)
      qf[ks] = *reinterpret_cast<const short8*>(
          Q + base + (size_t)(qw + lrow) * 1024 + ks * 32 + lgrp * 8);

    floatx4 oacc[4] = {};
    float m_run = -1e30f, l_run = 0.f;

    // prologue: stage tile 0 (previous pass's final barrier protects buffer reuse)
    stageK(0, 0);
    stageV(0, 0);
    __syncthreads();

    for (int kb = 0; kb < nkb; ++kb) {
      const int cur = kb & 1, nxt = cur ^ 1;
      if (kb + 1 < nkb) { stageK(nxt, kb + 1); stageV(nxt, kb + 1); }

      if (kb <= lastkb) {
        // ---- S^T = mfma(K, Q): s[nf][r] = S[q=lrow][k=nf*16+lgrp*4+r] (log2 units)
        floatx4 s[4];
        __builtin_amdgcn_s_setprio(1);
#pragma unroll
        for (int nf = 0; nf < 4; ++nf) {
          const int krow = nf * 16 + lrow;
          const short8 kf0 = *reinterpret_cast<const short8*>(
              &lds_k[cur][krow * 64 + ((lgrp) ^ (krow & 7)) * 8]);
          const short8 kf1 = *reinterpret_cast<const short8*>(
              &lds_k[cur][krow * 64 + ((4 + lgrp) ^ (krow & 7)) * 8]);
          floatx4 z = {};
          z = __builtin_amdgcn_mfma_f32_16x16x32_bf16(kf0, qf[0], z, 0, 0, 0);
          z = __builtin_amdgcn_mfma_f32_16x16x32_bf16(kf1, qf[1], z, 0, 0, 0);
          s[nf] = z;
        }
        __builtin_amdgcn_s_setprio(0);

        // ---- causal mask + row max
        const bool diag = (kb == lastkb);
        float vmax = -1e30f;
        if (diag) {
#pragma unroll
          for (int nf = 0; nf < 4; ++nf)
#pragma unroll
            for (int r = 0; r < 4; ++r) {
              const int kg = kb * 64 + nf * 16 + lgrp * 4 + r;
              const int qg = qw + lrow;
              float xv = s[nf][r];
              if (kg > qg) xv = -1e30f;
              s[nf][r] = xv;
              vmax = fmaxf(vmax, xv);
            }
        } else {
#pragma unroll
          for (int nf = 0; nf < 4; ++nf)
#pragma unroll
            for (int r = 0; r < 4; ++r) vmax = fmaxf(vmax, s[nf][r]);
        }
        vmax = fmaxf(vmax, __shfl_xor(vmax, 16, 64));
        vmax = fmaxf(vmax, __shfl_xor(vmax, 32, 64));

        // ---- defer-max online softmax (log2 domain, THR=8 -> P <= 256)
        if (__any(vmax > m_run + 8.f)) {
          const float mnew = fmaxf(m_run, vmax);
          const float alpha = exp2f(m_run - mnew);
          m_run = mnew;
          l_run *= alpha;
#pragma unroll
          for (int r = 0; r < 4; ++r) {
            const float a = __shfl(alpha, lgrp * 4 + r, 64);
#pragma unroll
            for (int nf = 0; nf < 4; ++nf) oacc[nf][r] *= a;
          }
        }

        // ---- P = exp2(s - m): pack 4 consecutive k per nf -> one b64 LDS write
        float psum = 0.f;
#pragma unroll
        for (int nf = 0; nf < 4; ++nf) {
          const float p0 = exp2f(s[nf][0] - m_run);
          const float p1 = exp2f(s[nf][1] - m_run);
          const float p2 = exp2f(s[nf][2] - m_run);
          const float p3 = exp2f(s[nf][3] - m_run);
          psum += (p0 + p1) + (p2 + p3);
          short4v pk;
          pk.x = f2bf(p0); pk.y = f2bf(p1); pk.z = f2bf(p2); pk.w = f2bf(p3);
          const int c8 = (nf * 4 + lgrp) ^ ((lrow & 7) << 1);
          *reinterpret_cast<short4v*>(&lds_p[w][lrow * 64 + c8 * 4]) = pk;
        }
        psum += __shfl_xor(psum, 16, 64);
        psum += __shfl_xor(psum, 32, 64);
        l_run += psum;

        // ---- PV: A = P (per-wave LDS), B-frag = V^T rows from lds_v [d][k]
        short8 pa[2];
#pragma unroll
        for (int ks = 0; ks < 2; ++ks) {
          const int c16 = (ks * 4 + lgrp) ^ (lrow & 7);
          pa[ks] = *reinterpret_cast<const short8*>(&lds_p[w][lrow * 64 + c16 * 8]);
        }
        __builtin_amdgcn_s_setprio(1);
#pragma unroll
        for (int nf = 0; nf < 4; ++nf) {
          const int drow = nf * 16 + lrow;
          const short8 vf0 = *reinterpret_cast<const short8*>(
              &lds_v[cur][drow * 64 + ((lgrp) ^ (drow & 7)) * 8]);
          const short8 vf1 = *reinterpret_cast<const short8*>(
              &lds_v[cur][drow * 64 + ((4 + lgrp) ^ (drow & 7)) * 8]);
          oacc[nf] = __builtin_amdgcn_mfma_f32_16x16x32_bf16(pa[0], vf0, oacc[nf], 0, 0, 0);
          oacc[nf] = __builtin_amdgcn_mfma_f32_16x16x32_bf16(pa[1], vf1, oacc[nf], 0, 0, 0);
        }
        __builtin_amdgcn_s_setprio(0);
      }

      __syncthreads();
    }

    // ---- epilogue: O rows = q = qw + lgrp*4 + r
#pragma unroll
    for (int r = 0; r < 4; ++r) {
      const float linv = 1.0f / __shfl(l_run, lgrp * 4 + r, 64);
      const int t = qw + lgrp * 4 + r;
#pragma unroll
      for (int nf = 0; nf < 4; ++nf)
        O[base + (size_t)t * 1024 + nf * 16 + lrow] = f2bf(oacc[nf][r] * linv);
    }
  }
}

// ---------------- launcher ----------------
extern "C" void kernel_launch(void* const* d_in, const int* in_sizes, int n_in,
                              void* d_out, int out_size, void* d_ws, size_t ws_size,
                              hipStream_t stream) {
  const float* x  = (const float*)d_in[0];
  const float* Wq = (const float*)d_in[1];
  const float* Wk = (const float*)d_in[2];
  const float* Wv = (const float*)d_in[3];
  const float* Wo = (const float*)d_in[4];

  uint8_t* ws = (uint8_t*)d_ws;
  short* xb  = (short*)(ws + 0);           // 8192x1024 bf16  (16 MiB)
  short* wqb = (short*)(ws + 16777216);    // 1024x1024 bf16  (2 MiB)
  short* wkb = (short*)(ws + 18874368);
  short* wvb = (short*)(ws + 20971520);
  short* wob = (short*)(ws + 23068672);
  short* Qb  = (short*)(ws + 25165824);    // 8192x1024 bf16
  short* Kb  = (short*)(ws + 41943040);
  short* Vt  = (short*)(ws + 58720256);    // [64 bh][64 d][2048 t] bf16
  short* Ob  = (short*)(ws + 75497472);
  if (ws_size < 92274688ull) return;  // fail loudly (output stays poisoned)

  const float qscale = 0.125f * LOG2E;     // fold head-scale + log2e into W_Q

  cvt_f32_bf16<<<8192, 256, 0, stream>>>(x, xb, 2097152, 1.0f);
  cvt_f32_bf16<<<1024, 256, 0, stream>>>(Wq, wqb, 262144, qscale);
  cvt_f32_bf16<<<1024, 256, 0, stream>>>(Wk, wkb, 262144, 1.0f);
  cvt_f32_bf16<<<1024, 256, 0, stream>>>(Wv, wvb, 262144, 1.0f);
  cvt_f32_bf16<<<1024, 256, 0, stream>>>(Wo, wob, 262144, 1.0f);

  gemm_qkv<<<dim3(64, 8, 3), 256, 0, stream>>>(xb, wqb, wkb, wvb, Qb, Kb, Vt);
  attn_fwd<<<dim3(8, 64), 512, 0, stream>>>(Qb, Kb, Vt, Ob);
  gemm_out<<<dim3(64, 8), 256, 0, stream>>>(Ob, wob, (float*)d_out);
}